// Round 1
// baseline (140.298 us; speedup 1.0000x reference)
//
#include <hip/hip_runtime.h>

// MonotoneActivation: per (b,g) group of ARITY=4 inputs, sort, barycentric
// interpolation on the 2^4 lattice, OUT_DIM=4 outputs.
// idx[0] == 15 always and params[:,15,:] == 1.0 (reference projects it), so
// the first corner contributes c0 * 1 -- saves one gather.

#define ARITY   4
#define GROUPS  256
#define OUT_DIM 4

__global__ __launch_bounds__(256) void mono_act_kernel(
    const float* __restrict__ X,
    const float* __restrict__ params,   // [GROUPS, 16, OUT_DIM]
    float* __restrict__ out,            // [B, GROUPS*OUT_DIM]
    int total)                          // B * GROUPS
{
    int tid = blockIdx.x * blockDim.x + threadIdx.x;
    if (tid >= total) return;
    int g = tid & (GROUPS - 1);

    // coalesced 16B load: 4 inputs of this group
    const float4 x = *reinterpret_cast<const float4*>(X + (size_t)tid * 4);
    float a0 = x.x, a1 = x.y, a2 = x.z, a3 = x.w;
    // track 1<<original_index directly
    int i0 = 1, i1 = 2, i2 = 4, i3 = 8;

    // stable sorting network (strict >): (0,1)(2,3)(0,2)(1,3)(1,2)
#define CEX(a, b, ia, ib)                                   \
    do {                                                    \
        if (a > b) {                                        \
            float _t = a; a = b; b = _t;                    \
            int _u = ia; ia = ib; ib = _u;                  \
        }                                                   \
    } while (0)
    CEX(a0, a1, i0, i1);
    CEX(a2, a3, i2, i3);
    CEX(a0, a2, i0, i2);
    CEX(a1, a3, i1, i3);
    CEX(a1, a2, i1, i2);
#undef CEX

    // barycentric coefficients
    float c0 = a0;
    float c1 = a1 - a0;
    float c2 = a2 - a1;
    float c3 = a3 - a2;

    // reversed-cumsum lattice indices (e0 == 15, corner == all-ones == 1.0)
    int e3 = i3;
    int e2 = e3 | i2;
    int e1 = e2 | i1;

    const float4* __restrict__ P =
        reinterpret_cast<const float4*>(params) + ((size_t)g << 4);
    float4 p1 = P[e1];
    float4 p2 = P[e2];
    float4 p3 = P[e3];

    float4 r;
    r.x = c0 + c1 * p1.x + c2 * p2.x + c3 * p3.x;
    r.y = c0 + c1 * p1.y + c2 * p2.y + c3 * p3.y;
    r.z = c0 + c1 * p1.z + c2 * p2.z + c3 * p3.z;
    r.w = c0 + c1 * p1.w + c2 * p2.w + c3 * p3.w;

    *reinterpret_cast<float4*>(out + (size_t)tid * 4) = r;
}

extern "C" void kernel_launch(void* const* d_in, const int* in_sizes, int n_in,
                              void* d_out, int out_size, void* d_ws, size_t ws_size,
                              hipStream_t stream) {
    const float* X      = (const float*)d_in[0];
    const float* params = (const float*)d_in[1];
    float* out          = (float*)d_out;

    int total = in_sizes[0] / ARITY;          // B * GROUPS = 4,194,304
    int block = 256;
    int grid  = (total + block - 1) / block;  // 16384

    mono_act_kernel<<<grid, block, 0, stream>>>(X, params, out, total);
}

// Round 2
// 117.540 us; speedup vs baseline: 1.1936x; 1.1936x over previous
//
#include <hip/hip_runtime.h>

// MonotoneActivation: per (b,g) group of ARITY=4 inputs, sort-4, barycentric
// interpolation over the 2^4 lattice, OUT_DIM=4 outputs.
//
// R1 design: the 64 KB params table caused scattered L2 gathers (64 lines per
// wave instruction). Stage half the table (128 groups = 32 KB) in LDS per
// block; block processes 32 batch rows of its 128-group chunk. All global
// traffic is then perfectly coalesced streaming. LDS layout [e][g] gives
// conflict-free ds_read_b128 (lanes = consecutive g = consecutive 16B chunks).

#define GROUPS        256
#define CHUNK_G       128                  // groups per block
#define ROWS_PER_BLK  32
#define BATCH         16384
#define BPC           (BATCH / ROWS_PER_BLK)   // 512
#define NBLOCKS       (2 * BPC)                // 1024 = 4 blocks/CU

__global__ __launch_bounds__(256, 4) void mono_act_kernel(
    const float* __restrict__ X,
    const float* __restrict__ params,   // [GROUPS, 16, 4] floats
    float* __restrict__ out)            // [BATCH, GROUPS*4]
{
    __shared__ float4 lut[16 * CHUNK_G];   // 32 KB: lut[e*CHUNK_G + g]

    const int t     = threadIdx.x;
    const int chunk = blockIdx.x & 1;        // which 128-group half
    const int slab  = blockIdx.x >> 1;       // which 32-row slab

    // ---- stage params chunk into LDS, transposed to [e][g] ----
    const float4* __restrict__ P = reinterpret_cast<const float4*>(params);
    #pragma unroll
    for (int i = 0; i < 8; ++i) {
        int idx = i * 256 + t;               // 0..2047 == e*128 + g
        int e   = idx >> 7;
        int g   = idx & (CHUNK_G - 1);
        lut[idx] = P[((size_t)(chunk * CHUNK_G + g) << 4) + e];
    }
    __syncthreads();

    // ---- compute: 256 threads cover 2 rows x 128 groups per iteration ----
    const int g    = t & (CHUNK_G - 1);
    const int rsub = t >> 7;                 // 0 or 1
    const int r0   = slab * ROWS_PER_BLK + rsub;

    // float4 index of (row r, this chunk, group g) in X/out
    const float4* __restrict__ X4 =
        reinterpret_cast<const float4*>(X) + (size_t)chunk * CHUNK_G + g;
    float4* __restrict__ O4 =
        reinterpret_cast<float4*>(out) + (size_t)chunk * CHUNK_G + g;

    #pragma unroll 4
    for (int k = 0; k < ROWS_PER_BLK / 2; ++k) {
        const size_t roff = (size_t)(r0 + 2 * k) * GROUPS;  // float4 units/row
        const float4 x = X4[roff];

        float a0 = x.x, a1 = x.y, a2 = x.z, a3 = x.w;
        int i0 = 1, i1 = 2, i2 = 4, i3 = 8;   // 1 << original index

        // stable sorting network (strict >): (0,1)(2,3)(0,2)(1,3)(1,2)
#define CEX(a, b, ia, ib)                                   \
        do {                                                \
            if (a > b) {                                    \
                float _t = a; a = b; b = _t;                \
                int _u = ia; ia = ib; ib = _u;              \
            }                                               \
        } while (0)
        CEX(a0, a1, i0, i1);
        CEX(a2, a3, i2, i3);
        CEX(a0, a2, i0, i2);
        CEX(a1, a3, i1, i3);
        CEX(a1, a2, i1, i2);
#undef CEX

        const float c0 = a0;
        const float c1 = a1 - a0;
        const float c2 = a2 - a1;
        const float c3 = a3 - a2;

        // reversed-cumsum lattice indices; e0==15 -> corner==1.0 (projected)
        const int e3 = i3;
        const int e2 = e3 | i2;
        const int e1 = e2 | i1;

        const float4 p1 = lut[(e1 << 7) + g];
        const float4 p2 = lut[(e2 << 7) + g];
        const float4 p3 = lut[(e3 << 7) + g];

        float4 r;
        r.x = c0 + c1 * p1.x + c2 * p2.x + c3 * p3.x;
        r.y = c0 + c1 * p1.y + c2 * p2.y + c3 * p3.y;
        r.z = c0 + c1 * p1.z + c2 * p2.z + c3 * p3.z;
        r.w = c0 + c1 * p1.w + c2 * p2.w + c3 * p3.w;

        O4[roff] = r;
    }
}

extern "C" void kernel_launch(void* const* d_in, const int* in_sizes, int n_in,
                              void* d_out, int out_size, void* d_ws, size_t ws_size,
                              hipStream_t stream) {
    const float* X      = (const float*)d_in[0];
    const float* params = (const float*)d_in[1];
    float* out          = (float*)d_out;

    mono_act_kernel<<<NBLOCKS, 256, 0, stream>>>(X, params, out);
}